// Round 1
// baseline (1128.374 us; speedup 1.0000x reference)
//
#include <hip/hip_runtime.h>

// Problem dims
#define HWP 65536   // H*W
#define BCH 200     // input channels
#define DCH 128     // feature dim
#define NSP 1024    // superpixels
#define KCH 64      // k-chunks for pooling partials

__device__ __forceinline__ float lrelu(float v) { return v > 0.f ? v : 0.01f * v; }

// ---------------------------------------------------------------------------
// K1: fused CNN_denoise: bn0 -> conv1x1(w1)+b1 -> lrelu -> bn1 -> conv1x1(w2)+b2 -> lrelu
// One block = 16 pixels. xf written to d_out (reused as scratch).
// ---------------------------------------------------------------------------
__global__ __launch_bounds__(256) void cnn_fused(
    const float* __restrict__ x,
    const float* __restrict__ bn0_g, const float* __restrict__ bn0_b,
    const float* __restrict__ w1, const float* __restrict__ b1,
    const float* __restrict__ bn1_g, const float* __restrict__ bn1_b,
    const float* __restrict__ w2, const float* __restrict__ b2,
    float* __restrict__ xf)
{
    __shared__ float xs[16 * BCH];   // 12.8 KB
    __shared__ float us[16 * DCH];   // 8 KB
    const int pix0 = blockIdx.x * 16;
    const int t = threadIdx.x;

    // stage 16 pixels x 200 ch, applying bn0 (coalesced: global idx = pix0*200 + i)
    for (int i = t; i < 16 * BCH; i += 256) {
        int b = i % BCH;
        xs[i] = bn0_g[b] * x[(size_t)pix0 * BCH + i] + bn0_b[b];
    }
    __syncthreads();

    const int d  = t & 127;
    const int ph = t >> 7;           // 0: pixels 0-7, 1: pixels 8-15
    float acc[8];
#pragma unroll
    for (int pp = 0; pp < 8; ++pp) acc[pp] = b1[d];
    for (int b = 0; b < BCH; ++b) {
        float wv = w1[b * DCH + d];
#pragma unroll
        for (int pp = 0; pp < 8; ++pp)
            acc[pp] += xs[(ph * 8 + pp) * BCH + b] * wv;
    }
#pragma unroll
    for (int pp = 0; pp < 8; ++pp) {
        float v = lrelu(acc[pp]);
        us[(ph * 8 + pp) * DCH + d] = bn1_g[d] * v + bn1_b[d];
    }
    __syncthreads();

    float acc2[8];
#pragma unroll
    for (int pp = 0; pp < 8; ++pp) acc2[pp] = b2[d];
    for (int dd = 0; dd < DCH; ++dd) {
        float wv = w2[dd * DCH + d];
#pragma unroll
        for (int pp = 0; pp < 8; ++pp)
            acc2[pp] += us[(ph * 8 + pp) * DCH + dd] * wv;
    }
#pragma unroll
    for (int pp = 0; pp < 8; ++pp)
        xf[(size_t)(pix0 + ph * 8 + pp) * DCH + d] = lrelu(acc2[pp]);
}

// ---------------------------------------------------------------------------
// K2: pooling partials. P_part[kc][n][d] = sum_{r in chunk} Q[r,n]*xf[r,d]
//     qs_part[kc][n]   = sum_{r in chunk} Q[r,n]          (fused colsum)
// grid = (8 n-tiles of 128, 64 k-chunks of 1024 rows). Deterministic (no atomics).
// ---------------------------------------------------------------------------
__global__ __launch_bounds__(256) void pool_partial(
    const float* __restrict__ Q, const float* __restrict__ xf,
    float* __restrict__ P_part, float* __restrict__ qs_part)
{
    __shared__ float qs_l[16 * 128];
    __shared__ float xs_l[16 * 128];
    const int n0 = blockIdx.x * 128;
    const int kc = blockIdx.y;
    const int r0 = kc * (HWP / KCH);   // 1024 rows per chunk
    const int t = threadIdx.x;
    const int tn = t >> 4;             // 0..15  -> 8 n's each
    const int td = t & 15;             // 0..15  -> 8 d's each

    float acc[8][8];
#pragma unroll
    for (int i = 0; i < 8; ++i)
#pragma unroll
        for (int j = 0; j < 8; ++j) acc[i][j] = 0.f;
    float qacc = 0.f;

    for (int g = 0; g < (HWP / KCH) / 16; ++g) {   // 64 row-groups of 16
        const int rg = r0 + g * 16;
        __syncthreads();
        for (int i = t; i < 2048; i += 256) {
            int row = i >> 7, col = i & 127;
            qs_l[i] = Q[(size_t)(rg + row) * NSP + n0 + col];
            xs_l[i] = xf[(size_t)(rg + row) * DCH + col];
        }
        __syncthreads();
        if (t < 128) {
#pragma unroll
            for (int row = 0; row < 16; ++row) qacc += qs_l[row * 128 + t];
        }
        for (int row = 0; row < 16; ++row) {
            float4 qa = *(const float4*)&qs_l[row * 128 + tn * 8];
            float4 qb = *(const float4*)&qs_l[row * 128 + tn * 8 + 4];
            float4 xa = *(const float4*)&xs_l[row * 128 + td * 8];
            float4 xb = *(const float4*)&xs_l[row * 128 + td * 8 + 4];
            float qv[8] = {qa.x, qa.y, qa.z, qa.w, qb.x, qb.y, qb.z, qb.w};
            float xv[8] = {xa.x, xa.y, xa.z, xa.w, xb.x, xb.y, xb.z, xb.w};
#pragma unroll
            for (int i = 0; i < 8; ++i)
#pragma unroll
                for (int j = 0; j < 8; ++j)
                    acc[i][j] += qv[i] * xv[j];
        }
    }

#pragma unroll
    for (int i = 0; i < 8; ++i)
#pragma unroll
        for (int j = 0; j < 8; ++j)
            P_part[(size_t)kc * (NSP * DCH) + (size_t)(n0 + tn * 8 + i) * DCH + td * 8 + j] = acc[i][j];
    if (t < 128) qs_part[kc * NSP + n0 + t] = qacc;
}

// ---------------------------------------------------------------------------
// K3: reduce partials -> h0[n,d] = sum_k P_part / sum_k qs_part[n]
// ---------------------------------------------------------------------------
__global__ __launch_bounds__(256) void reduce_h0(
    const float* __restrict__ P_part, const float* __restrict__ qs_part,
    float* __restrict__ h)
{
    const int idx = blockIdx.x * 256 + threadIdx.x;   // 0..131071
    const int n = idx >> 7;
    float s = 0.f;
    for (int k = 0; k < KCH; ++k) s += P_part[(size_t)k * (NSP * DCH) + idx];
    float qs = 0.f;
    for (int k = 0; k < KCH; ++k) qs += qs_part[k * NSP + n];
    h[idx] = s / qs;
}

// ---------------------------------------------------------------------------
// K4: dinv[n] = (rowsum(adj)[n] + 1)^-1/2    (g = adj + I)
// ---------------------------------------------------------------------------
__global__ __launch_bounds__(256) void dinv_k(const float* __restrict__ adj,
                                              float* __restrict__ dinv)
{
    __shared__ float red[256];
    const int n = blockIdx.x;
    const int t = threadIdx.x;
    float4 v = *(const float4*)&adj[(size_t)n * NSP + t * 4];
    red[t] = v.x + v.y + v.z + v.w;
    __syncthreads();
    for (int off = 128; off > 0; off >>= 1) {
        if (t < off) red[t] += red[t + off];
        __syncthreads();
    }
    if (t == 0) dinv[n] = rsqrtf(red[0] + 1.0f);
}

// ---------------------------------------------------------------------------
// K5: hb2[j,d] = dinv[j] * (gg[d]*h[j,d] + gb[d])   (BN + left D^-1/2)
// ---------------------------------------------------------------------------
__global__ __launch_bounds__(256) void hb2_k(
    const float* __restrict__ h, const float* __restrict__ dinv,
    const float* __restrict__ gg, const float* __restrict__ gb,
    float* __restrict__ hb2)
{
    const int idx = blockIdx.x * 256 + threadIdx.x;
    const int j = idx >> 7, d = idx & 127;
    hb2[idx] = dinv[j] * (gg[d] * h[idx] + gb[d]);
}

// ---------------------------------------------------------------------------
// K6: m1[r,d] = dinv[r] * ( (adj @ hb2)[r,d] + hb2[r,d] )   == gn @ hb
// block = 16 rows, adj staged in 256-col chunks
// ---------------------------------------------------------------------------
__global__ __launch_bounds__(256) void m1_k(
    const float* __restrict__ adj, const float* __restrict__ hb2,
    const float* __restrict__ dinv, float* __restrict__ m1)
{
    __shared__ float adjL[16 * 256];   // 16 KB
    const int r0 = blockIdx.x * 16;
    const int t = threadIdx.x;
    const int d = t & 127, ph = t >> 7;
    float acc[8];
#pragma unroll
    for (int pp = 0; pp < 8; ++pp) acc[pp] = 0.f;

    for (int jc = 0; jc < 4; ++jc) {
        __syncthreads();
        for (int i = t; i < 4096; i += 256) {
            int row = i >> 8, col = i & 255;
            adjL[i] = adj[(size_t)(r0 + row) * NSP + jc * 256 + col];
        }
        __syncthreads();
        for (int jj = 0; jj < 256; ++jj) {
            float hv = hb2[(size_t)(jc * 256 + jj) * DCH + d];
#pragma unroll
            for (int pp = 0; pp < 8; ++pp)
                acc[pp] += adjL[(ph * 8 + pp) * 256 + jj] * hv;
        }
    }
#pragma unroll
    for (int pp = 0; pp < 8; ++pp) {
        int r = r0 + ph * 8 + pp;
        m1[(size_t)r * DCH + d] = dinv[r] * (acc[pp] + hb2[(size_t)r * DCH + d]);
    }
}

// ---------------------------------------------------------------------------
// K7: h_next[r,e] = lrelu( (m1 @ W)[r,e] + bias[e] )
// ---------------------------------------------------------------------------
__global__ __launch_bounds__(256) void gcnw_k(
    const float* __restrict__ m1, const float* __restrict__ W,
    const float* __restrict__ bias, float* __restrict__ hout)
{
    __shared__ float ms[16 * 128];
    const int r0 = blockIdx.x * 16;
    const int t = threadIdx.x;
    for (int i = t; i < 2048; i += 256) ms[i] = m1[(size_t)r0 * DCH + i];
    __syncthreads();
    const int e = t & 127, ph = t >> 7;
    float acc[8];
#pragma unroll
    for (int pp = 0; pp < 8; ++pp) acc[pp] = bias[e];
    for (int dd = 0; dd < DCH; ++dd) {
        float wv = W[dd * DCH + e];
#pragma unroll
        for (int pp = 0; pp < 8; ++pp)
            acc[pp] += ms[(ph * 8 + pp) * DCH + dd] * wv;
    }
#pragma unroll
    for (int pp = 0; pp < 8; ++pp)
        hout[(size_t)(r0 + ph * 8 + pp) * DCH + e] = lrelu(acc[pp]);
}

// ---------------------------------------------------------------------------
// K8: out = Q @ h    [65536,1024] @ [1024,128]
// block = 16 rows, Q staged in 256-col chunks, h broadcast from L2
// ---------------------------------------------------------------------------
__global__ __launch_bounds__(256) void out_k(
    const float* __restrict__ Q, const float* __restrict__ h,
    float* __restrict__ out)
{
    __shared__ float Qs[16 * 256];   // 16 KB
    const int r0 = blockIdx.x * 16;
    const int t = threadIdx.x;
    const int d = t & 127, ph = t >> 7;
    float acc[8];
#pragma unroll
    for (int pp = 0; pp < 8; ++pp) acc[pp] = 0.f;

    for (int nc = 0; nc < 4; ++nc) {
        __syncthreads();
        for (int i = t; i < 4096; i += 256) {
            int row = i >> 8, col = i & 255;
            Qs[i] = Q[(size_t)(r0 + row) * NSP + nc * 256 + col];
        }
        __syncthreads();
        for (int nn = 0; nn < 256; ++nn) {
            float hv = h[(size_t)(nc * 256 + nn) * DCH + d];
#pragma unroll
            for (int pp = 0; pp < 8; ++pp)
                acc[pp] += Qs[(ph * 8 + pp) * 256 + nn] * hv;
        }
    }
#pragma unroll
    for (int pp = 0; pp < 8; ++pp)
        out[(size_t)(r0 + ph * 8 + pp) * DCH + d] = acc[pp];
}

// ---------------------------------------------------------------------------
extern "C" void kernel_launch(void* const* d_in, const int* in_sizes, int n_in,
                              void* d_out, int out_size, void* d_ws, size_t ws_size,
                              hipStream_t stream)
{
    const float* x      = (const float*)d_in[0];
    const float* Q      = (const float*)d_in[1];
    const float* adj    = (const float*)d_in[2];
    const float* bn0_g  = (const float*)d_in[3];
    const float* bn0_b  = (const float*)d_in[4];
    const float* w1     = (const float*)d_in[5];
    const float* b1     = (const float*)d_in[6];
    const float* bn1_g  = (const float*)d_in[7];
    const float* bn1_b  = (const float*)d_in[8];
    const float* w2     = (const float*)d_in[9];
    const float* b2     = (const float*)d_in[10];
    const float* gbn_g  = (const float*)d_in[11];   // (3,128)
    const float* gbn_b  = (const float*)d_in[12];   // (3,128)
    const float* gcn_w  = (const float*)d_in[13];   // (3,128,128)
    const float* gcn_b  = (const float*)d_in[14];   // (3,128)

    float* out = (float*)d_out;
    float* ws  = (float*)d_ws;

    // workspace layout (floats): ~36 MB total
    float* P_part  = ws;                              // KCH*NSP*DCH = 8388608
    float* qs_part = P_part + (size_t)KCH * NSP * DCH; // KCH*NSP     = 65536
    float* hA      = qs_part + (size_t)KCH * NSP;     // 131072
    float* hB      = hA + NSP * DCH;                  // 131072
    float* m1b     = hB + NSP * DCH;                  // 131072
    float* hb2b    = m1b + NSP * DCH;                 // 131072
    float* dinvb   = hb2b + NSP * DCH;                // 1024

    float* xf = out;   // reuse d_out as xf scratch (dead until out_k)

    cnn_fused<<<HWP / 16, 256, 0, stream>>>(x, bn0_g, bn0_b, w1, b1,
                                            bn1_g, bn1_b, w2, b2, xf);
    pool_partial<<<dim3(NSP / 128, KCH), 256, 0, stream>>>(Q, xf, P_part, qs_part);
    reduce_h0<<<(NSP * DCH) / 256, 256, 0, stream>>>(P_part, qs_part, hA);
    dinv_k<<<NSP, 256, 0, stream>>>(adj, dinvb);

    const float* hcur = hA;
    float* hnext = hB;
    for (int i = 0; i < 3; ++i) {
        hb2_k<<<(NSP * DCH) / 256, 256, 0, stream>>>(hcur, dinvb,
                                                     gbn_g + i * DCH, gbn_b + i * DCH, hb2b);
        m1_k<<<NSP / 16, 256, 0, stream>>>(adj, hb2b, dinvb, m1b);
        gcnw_k<<<NSP / 16, 256, 0, stream>>>(m1b, gcn_w + (size_t)i * DCH * DCH,
                                             gcn_b + i * DCH, hnext);
        const float* tmp = hcur;
        hcur = hnext;
        hnext = (float*)tmp;
    }

    out_k<<<HWP / 16, 256, 0, stream>>>(Q, hcur, out);
}

// Round 2
// 349.422 us; speedup vs baseline: 3.2293x; 3.2293x over previous
//
#include <hip/hip_runtime.h>

#define HWP 65536
#define NSP 1024
#define DCH 128
#define KC  64          // pooling k-chunks (rows per chunk = 1024)

typedef float f32x4 __attribute__((ext_vector_type(4)));
typedef short bf16x8 __attribute__((ext_vector_type(8)));
typedef short bf16x4 __attribute__((ext_vector_type(4)));

__device__ __forceinline__ float lrelu(float v) { return v > 0.f ? v : 0.01f * v; }

__device__ __forceinline__ short f2bf(float f) {
    unsigned u = __builtin_bit_cast(unsigned, f);
    u += 0x7fffu + ((u >> 16) & 1u);          // RNE
    return (short)(u >> 16);
}

// ---------------------------------------------------------------------------
// prep_w: fold bn0 into w1 (-> w1t, bf16 fragment-order, K padded 200->224),
//         fold bn1 into w2 (-> w2t), compute fused biases b1f/b2f.
// fragment order: [ks][nf][lane][8]; elem (ks,nf,l,j) = W'[ks*32+(l>>4)*8+j][nf*16+(l&15)]
// ---------------------------------------------------------------------------
__global__ __launch_bounds__(256) void prep_w(
    const float* __restrict__ w1, const float* __restrict__ b1,
    const float* __restrict__ bn0_g, const float* __restrict__ bn0_b,
    const float* __restrict__ w2, const float* __restrict__ b2,
    const float* __restrict__ bn1_g, const float* __restrict__ bn1_b,
    short* __restrict__ w1t, short* __restrict__ w2t,
    float* __restrict__ b1f, float* __restrict__ b2f)
{
    int t = blockIdx.x * 256 + threadIdx.x;
    if (t < 7 * 8 * 64 * 8) {
        int j = t & 7, lane = (t >> 3) & 63, nf = (t >> 9) & 7, ks = t >> 12;
        int ch = ks * 32 + (lane >> 4) * 8 + j;
        int d  = nf * 16 + (lane & 15);
        float v = (ch < 200) ? bn0_g[ch] * w1[ch * 128 + d] : 0.f;
        w1t[t] = f2bf(v);
    }
    if (t < 4 * 8 * 64 * 8) {
        int j = t & 7, lane = (t >> 3) & 63, nf = (t >> 9) & 7, ks = t >> 12;
        int k = ks * 32 + (lane >> 4) * 8 + j;
        int d = nf * 16 + (lane & 15);
        w2t[t] = f2bf(bn1_g[k] * w2[k * 128 + d]);
    }
    if (t < 128) {
        float s1 = b1[t], s2 = b2[t];
        for (int ch = 0; ch < 200; ++ch) s1 += bn0_b[ch] * w1[ch * 128 + t];
        for (int k = 0; k < 128; ++k)   s2 += bn1_b[k] * w2[k * 128 + t];
        b1f[t] = s1; b2f[t] = s2;
    }
}

// ---------------------------------------------------------------------------
// cnn_mfma: xfT[d][pix] (bf16) = lrelu( lrelu(x@w1'+b1') @ w2' + b2' )
// block = 128 threads = 2 waves; each wave: 64 pixels x 128 d.
// ---------------------------------------------------------------------------
__global__ __launch_bounds__(128) void cnn_mfma(
    const float* __restrict__ x, const short* __restrict__ w1t,
    const float* __restrict__ b1f, const short* __restrict__ w2t,
    const float* __restrict__ b2f, short* __restrict__ xfT)
{
    __shared__ __align__(16) short a2[2][4][4][64][8];   // 32 KB
    const int t = threadIdx.x;
    const int w = t >> 6, l = t & 63;
    const int q = l >> 4, li = l & 15;
    const int pix0 = blockIdx.x * 128 + w * 64;

    f32x4 acc[4][8];
#pragma unroll
    for (int nf = 0; nf < 8; ++nf) {
        float bv = b1f[nf * 16 + li];
#pragma unroll
        for (int mf = 0; mf < 4; ++mf) acc[mf][nf] = (f32x4){bv, bv, bv, bv};
    }

    // layer 1: K = 224 (7 steps of 32), tail step only q==0 valid (ch 192..199)
    for (int ks = 0; ks < 7; ++ks) {
        bf16x8 a[4];
        if (ks < 6 || q == 0) {
            int k0 = ks * 32 + q * 8;
#pragma unroll
            for (int mf = 0; mf < 4; ++mf) {
                const float* sp = &x[(size_t)(pix0 + mf * 16 + li) * 200 + k0];
                float4 u = *(const float4*)sp;
                float4 v = *(const float4*)(sp + 4);
                a[mf][0] = f2bf(u.x); a[mf][1] = f2bf(u.y);
                a[mf][2] = f2bf(u.z); a[mf][3] = f2bf(u.w);
                a[mf][4] = f2bf(v.x); a[mf][5] = f2bf(v.y);
                a[mf][6] = f2bf(v.z); a[mf][7] = f2bf(v.w);
            }
        } else {
#pragma unroll
            for (int mf = 0; mf < 4; ++mf)
#pragma unroll
                for (int j = 0; j < 8; ++j) a[mf][j] = 0;
        }
#pragma unroll
        for (int nf = 0; nf < 8; ++nf) {
            bf16x8 b = *(const bf16x8*)&w1t[((ks * 8 + nf) * 64 + l) * 8];
#pragma unroll
            for (int mf = 0; mf < 4; ++mf)
                acc[mf][nf] = __builtin_amdgcn_mfma_f32_16x16x32_bf16(a[mf], b, acc[mf][nf], 0, 0, 0);
        }
    }

    // lrelu -> bf16 -> wave-private LDS in layer-2 A-fragment order
#pragma unroll
    for (int mf = 0; mf < 4; ++mf)
#pragma unroll
        for (int nf = 0; nf < 8; ++nf)
#pragma unroll
            for (int j = 0; j < 4; ++j) {
                float v = lrelu(acc[mf][nf][j]);
                int row = mf * 16 + q * 4 + j;         // pixel-in-wave
                int col = nf * 16 + li;                // d1 = layer-2 k
                int ks2 = col >> 5;
                int lane2 = (row & 15) + (((col & 31) >> 3) << 4);
                a2[w][ks2][mf][lane2][col & 7] = f2bf(v);
            }
    __syncthreads();

    f32x4 acc2[4][8];
#pragma unroll
    for (int nf = 0; nf < 8; ++nf) {
        float bv = b2f[nf * 16 + li];
#pragma unroll
        for (int mf = 0; mf < 4; ++mf) acc2[mf][nf] = (f32x4){bv, bv, bv, bv};
    }
#pragma unroll
    for (int ks = 0; ks < 4; ++ks) {
        bf16x8 a[4];
#pragma unroll
        for (int mf = 0; mf < 4; ++mf)
            a[mf] = *(const bf16x8*)&a2[w][ks][mf][l][0];
#pragma unroll
        for (int nf = 0; nf < 8; ++nf) {
            bf16x8 b = *(const bf16x8*)&w2t[((ks * 8 + nf) * 64 + l) * 8];
#pragma unroll
            for (int mf = 0; mf < 4; ++mf)
                acc2[mf][nf] = __builtin_amdgcn_mfma_f32_16x16x32_bf16(a[mf], b, acc2[mf][nf], 0, 0, 0);
        }
    }

    // lrelu -> bf16 -> xfT[d][pix], 8B store per fragment
#pragma unroll
    for (int mf = 0; mf < 4; ++mf)
#pragma unroll
        for (int nf = 0; nf < 8; ++nf) {
            bf16x4 p;
#pragma unroll
            for (int j = 0; j < 4; ++j) p[j] = f2bf(lrelu(acc2[mf][nf][j]));
            int d2 = nf * 16 + li;
            int pix = pix0 + mf * 16 + q * 4;
            *(bf16x4*)&xfT[(size_t)d2 * HWP + pix] = p;
        }
}

// ---------------------------------------------------------------------------
// pool_mfma: P_part[chunk][n][d] = sum_{r in chunk} Q[r,n]*xf[r,d]  (MFMA)
//            qs_part[chunk][n]   = sum Q[r,n]  via all-ones B fragment
// grid (8 nblk, KC); block 256 = 4 waves (2 n-halves x 2 d-halves), wave 64x64
// ---------------------------------------------------------------------------
__device__ __forceinline__ void pool_loadA(float (&dst)[4][8], const float* __restrict__ Q,
                                           int rbase, int ncol0)
{
#pragma unroll
    for (int mf = 0; mf < 4; ++mf) {
        const float* sp = &Q[(size_t)rbase * NSP + ncol0 + mf * 16];
#pragma unroll
        for (int j = 0; j < 8; ++j) dst[mf][j] = sp[(size_t)j * NSP];
    }
}
__device__ __forceinline__ void pool_loadB(bf16x8 (&dst)[4], const short* __restrict__ xfT,
                                           int dcol0, int rbase)
{
#pragma unroll
    for (int nf = 0; nf < 4; ++nf)
        dst[nf] = *(const bf16x8*)&xfT[(size_t)(dcol0 + nf * 16) * HWP + rbase];
}
__device__ __forceinline__ void cvtA(bf16x8 (&bf)[4], const float (&src)[4][8])
{
#pragma unroll
    for (int mf = 0; mf < 4; ++mf)
#pragma unroll
        for (int j = 0; j < 8; ++j) bf[mf][j] = f2bf(src[mf][j]);
}

__global__ __launch_bounds__(256, 2) void pool_mfma(
    const float* __restrict__ Q, const short* __restrict__ xfT,
    float* __restrict__ P_part, float* __restrict__ qs_part)
{
    const int t = threadIdx.x;
    const int wid = t >> 6, l = t & 63;
    const int q = l >> 4, li = l & 15;
    const int n0 = blockIdx.x * 128 + (wid >> 1) * 64;
    const int d0 = (wid & 1) * 64;
    const int chunk = blockIdx.y;
    const int r0 = chunk * 1024;
    const int ncol0 = n0 + li;
    const int dcol0 = d0 + li;

    f32x4 acc[4][4];
    f32x4 accq[4];
#pragma unroll
    for (int mf = 0; mf < 4; ++mf) {
        accq[mf] = (f32x4){0.f, 0.f, 0.f, 0.f};
#pragma unroll
        for (int nf = 0; nf < 4; ++nf) acc[mf][nf] = (f32x4){0.f, 0.f, 0.f, 0.f};
    }
    bf16x8 bone;
    {
        short onev = (li == 0) ? (short)0x3F80 : (short)0;
#pragma unroll
        for (int j = 0; j < 8; ++j) bone[j] = onev;
    }

    float a0[4][8], a1[4][8];
    bf16x8 b0[4], b1v[4];
    pool_loadA(a0, Q, r0 + q * 8, ncol0);
    pool_loadB(b0, xfT, dcol0, r0 + q * 8);

    for (int ks = 0; ks < 32; ks += 2) {
        pool_loadA(a1, Q, r0 + (ks + 1) * 32 + q * 8, ncol0);
        pool_loadB(b1v, xfT, dcol0, r0 + (ks + 1) * 32 + q * 8);
        {
            bf16x8 abf[4]; cvtA(abf, a0);
#pragma unroll
            for (int mf = 0; mf < 4; ++mf) {
#pragma unroll
                for (int nf = 0; nf < 4; ++nf)
                    acc[mf][nf] = __builtin_amdgcn_mfma_f32_16x16x32_bf16(abf[mf], b0[nf], acc[mf][nf], 0, 0, 0);
                if (d0 == 0)
                    accq[mf] = __builtin_amdgcn_mfma_f32_16x16x32_bf16(abf[mf], bone, accq[mf], 0, 0, 0);
            }
        }
        if (ks + 2 < 32) {
            pool_loadA(a0, Q, r0 + (ks + 2) * 32 + q * 8, ncol0);
            pool_loadB(b0, xfT, dcol0, r0 + (ks + 2) * 32 + q * 8);
        }
        {
            bf16x8 abf[4]; cvtA(abf, a1);
#pragma unroll
            for (int mf = 0; mf < 4; ++mf) {
#pragma unroll
                for (int nf = 0; nf < 4; ++nf)
                    acc[mf][nf] = __builtin_amdgcn_mfma_f32_16x16x32_bf16(abf[mf], b1v[nf], acc[mf][nf], 0, 0, 0);
                if (d0 == 0)
                    accq[mf] = __builtin_amdgcn_mfma_f32_16x16x32_bf16(abf[mf], bone, accq[mf], 0, 0, 0);
            }
        }
    }

#pragma unroll
    for (int mf = 0; mf < 4; ++mf)
#pragma unroll
        for (int nf = 0; nf < 4; ++nf)
#pragma unroll
            for (int j = 0; j < 4; ++j) {
                int n = n0 + mf * 16 + q * 4 + j;
                int d = d0 + nf * 16 + li;
                P_part[((size_t)chunk * NSP + n) * DCH + d] = acc[mf][nf][j];
            }
    if (d0 == 0 && li == 0)
#pragma unroll
        for (int mf = 0; mf < 4; ++mf)
#pragma unroll
            for (int j = 0; j < 4; ++j)
                qs_part[chunk * NSP + n0 + mf * 16 + q * 4 + j] = accq[mf][j];
}

// ---------------------------------------------------------------------------
__global__ __launch_bounds__(256) void reduce_h0(
    const float* __restrict__ P_part, const float* __restrict__ qs_part,
    float* __restrict__ h)
{
    const int idx = blockIdx.x * 256 + threadIdx.x;
    const int n = idx >> 7;
    float s = 0.f;
    for (int k = 0; k < KC; ++k) s += P_part[(size_t)k * (NSP * DCH) + idx];
    float qs = 0.f;
    for (int k = 0; k < KC; ++k) qs += qs_part[k * NSP + n];
    h[idx] = s / qs;
}

// ---------------------------------------------------------------------------
__global__ __launch_bounds__(256) void dinv_k(const float* __restrict__ adj,
                                              float* __restrict__ dinv)
{
    __shared__ float red[256];
    const int n = blockIdx.x;
    const int t = threadIdx.x;
    float4 v = *(const float4*)&adj[(size_t)n * NSP + t * 4];
    red[t] = v.x + v.y + v.z + v.w;
    __syncthreads();
    for (int off = 128; off > 0; off >>= 1) {
        if (t < off) red[t] += red[t + off];
        __syncthreads();
    }
    if (t == 0) dinv[n] = rsqrtf(red[0] + 1.0f);
}

__global__ __launch_bounds__(256) void hb2_k(
    const float* __restrict__ h, const float* __restrict__ dinv,
    const float* __restrict__ gg, const float* __restrict__ gb,
    float* __restrict__ hb2)
{
    const int idx = blockIdx.x * 256 + threadIdx.x;
    const int j = idx >> 7, d = idx & 127;
    hb2[idx] = dinv[j] * (gg[d] * h[idx] + gb[d]);
}

// m1 partials: m1p[kc][r][d] = (adj[:, kc*256:+256] @ hb2[kc*256:+256, :])[r,d]
__global__ __launch_bounds__(256) void m1_k(
    const float* __restrict__ adj, const float* __restrict__ hb2,
    float* __restrict__ m1p)
{
    __shared__ float adjL[16 * 256];
    const int r0 = blockIdx.x * 16;
    const int jc = blockIdx.y;
    const int t = threadIdx.x;
    const int d = t & 127, ph = t >> 7;
    float acc[8];
#pragma unroll
    for (int pp = 0; pp < 8; ++pp) acc[pp] = 0.f;
    for (int i = t; i < 4096; i += 256) {
        int row = i >> 8, col = i & 255;
        adjL[i] = adj[(size_t)(r0 + row) * NSP + jc * 256 + col];
    }
    __syncthreads();
    for (int jj = 0; jj < 256; ++jj) {
        float hv = hb2[(size_t)(jc * 256 + jj) * DCH + d];
#pragma unroll
        for (int pp = 0; pp < 8; ++pp)
            acc[pp] += adjL[(ph * 8 + pp) * 256 + jj] * hv;
    }
#pragma unroll
    for (int pp = 0; pp < 8; ++pp)
        m1p[(size_t)jc * (NSP * DCH) + (size_t)(r0 + ph * 8 + pp) * DCH + d] = acc[pp];
}

// h_next = lrelu( (dinv_r*(sum m1p + hb2)) @ W + bias )
__global__ __launch_bounds__(256) void gcnw_k(
    const float* __restrict__ m1p, const float* __restrict__ hb2,
    const float* __restrict__ dinv, const float* __restrict__ W,
    const float* __restrict__ bias, float* __restrict__ hout)
{
    __shared__ float ms[16 * 128];
    const int r0 = blockIdx.x * 16;
    const int t = threadIdx.x;
    for (int i = t; i < 2048; i += 256) {
        int r = r0 + (i >> 7);
        float s = hb2[(size_t)r * DCH + (i & 127)];
#pragma unroll
        for (int kc = 0; kc < 4; ++kc)
            s += m1p[(size_t)kc * (NSP * DCH) + (size_t)r0 * DCH + i];
        ms[i] = dinv[r] * s;
    }
    __syncthreads();
    const int e = t & 127, ph = t >> 7;
    float acc[8];
#pragma unroll
    for (int pp = 0; pp < 8; ++pp) acc[pp] = bias[e];
    for (int dd = 0; dd < 128; ++dd) {
        float wv = W[dd * 128 + e];
#pragma unroll
        for (int pp = 0; pp < 8; ++pp)
            acc[pp] += ms[(ph * 8 + pp) * 128 + dd] * wv;
    }
#pragma unroll
    for (int pp = 0; pp < 8; ++pp)
        hout[(size_t)(r0 + ph * 8 + pp) * DCH + e] = lrelu(acc[pp]);
}

// htb fragment order: elem (ks,nf,l,j) = h[(ks*32+(l>>4)*8+j)*128 + nf*16+(l&15)]
__global__ __launch_bounds__(256) void htprep(const float* __restrict__ h,
                                              short* __restrict__ htb)
{
    int t = blockIdx.x * 256 + threadIdx.x;
    int j = t & 7, lane = (t >> 3) & 63, nf = (t >> 9) & 7, ks = t >> 12;
    htb[t] = f2bf(h[(ks * 32 + (lane >> 4) * 8 + j) * 128 + nf * 16 + (lane & 15)]);
}

// ---------------------------------------------------------------------------
// out_mfma: out[r,d] = sum_n Q[r,n]*h3[n,d], zero-LDS MFMA
// block 256 = 4 waves (2 row-halves x 2 d-halves), wave 64x64; grid 512
// ---------------------------------------------------------------------------
__device__ __forceinline__ void out_loadA(float (&dst)[4][8], const float* __restrict__ Q,
                                          int rrow0, int k0)
{
#pragma unroll
    for (int mf = 0; mf < 4; ++mf) {
        const float* sp = &Q[(size_t)(rrow0 + mf * 16) * NSP + k0];
        float4 u = *(const float4*)sp;
        float4 v = *(const float4*)(sp + 4);
        dst[mf][0] = u.x; dst[mf][1] = u.y; dst[mf][2] = u.z; dst[mf][3] = u.w;
        dst[mf][4] = v.x; dst[mf][5] = v.y; dst[mf][6] = v.z; dst[mf][7] = v.w;
    }
}
__device__ __forceinline__ void out_loadB(bf16x8 (&dst)[4], const short* __restrict__ htb,
                                          int ks, int nfbase, int l)
{
#pragma unroll
    for (int nf = 0; nf < 4; ++nf)
        dst[nf] = *(const bf16x8*)&htb[((ks * 8 + nfbase + nf) * 64 + l) * 8];
}

__global__ __launch_bounds__(256, 2) void out_mfma(
    const float* __restrict__ Q, const short* __restrict__ htb,
    float* __restrict__ out)
{
    const int t = threadIdx.x;
    const int wid = t >> 6, l = t & 63;
    const int q = l >> 4, li = l & 15;
    const int r0 = blockIdx.x * 128 + (wid >> 1) * 64;
    const int d0 = (wid & 1) * 64;
    const int rrow0 = r0 + li;
    const int nfb = d0 >> 4;

    f32x4 acc[4][4];
#pragma unroll
    for (int mf = 0; mf < 4; ++mf)
#pragma unroll
        for (int nf = 0; nf < 4; ++nf) acc[mf][nf] = (f32x4){0.f, 0.f, 0.f, 0.f};

    float a0[4][8], a1[4][8];
    bf16x8 b0[4], b1v[4];
    out_loadA(a0, Q, rrow0, q * 8);
    out_loadB(b0, htb, 0, nfb, l);

    for (int ks = 0; ks < 32; ks += 2) {
        out_loadA(a1, Q, rrow0, (ks + 1) * 32 + q * 8);
        out_loadB(b1v, htb, ks + 1, nfb, l);
        {
            bf16x8 abf[4]; cvtA(abf, a0);
#pragma unroll
            for (int mf = 0; mf < 4; ++mf)
#pragma unroll
                for (int nf = 0; nf < 4; ++nf)
                    acc[mf][nf] = __builtin_amdgcn_mfma_f32_16x16x32_bf16(abf[mf], b0[nf], acc[mf][nf], 0, 0, 0);
        }
        if (ks + 2 < 32) {
            out_loadA(a0, Q, rrow0, (ks + 2) * 32 + q * 8);
            out_loadB(b0, htb, ks + 2, nfb, l);
        }
        {
            bf16x8 abf[4]; cvtA(abf, a1);
#pragma unroll
            for (int mf = 0; mf < 4; ++mf)
#pragma unroll
                for (int nf = 0; nf < 4; ++nf)
                    acc[mf][nf] = __builtin_amdgcn_mfma_f32_16x16x32_bf16(abf[mf], b1v[nf], acc[mf][nf], 0, 0, 0);
        }
    }

#pragma unroll
    for (int mf = 0; mf < 4; ++mf)
#pragma unroll
        for (int nf = 0; nf < 4; ++nf)
#pragma unroll
            for (int j = 0; j < 4; ++j)
                out[(size_t)(r0 + mf * 16 + q * 4 + j) * DCH + d0 + nf * 16 + li] = acc[mf][nf][j];
}

// ---------------------------------------------------------------------------
extern "C" void kernel_launch(void* const* d_in, const int* in_sizes, int n_in,
                              void* d_out, int out_size, void* d_ws, size_t ws_size,
                              hipStream_t stream)
{
    const float* x      = (const float*)d_in[0];
    const float* Q      = (const float*)d_in[1];
    const float* adj    = (const float*)d_in[2];
    const float* bn0_g  = (const float*)d_in[3];
    const float* bn0_b  = (const float*)d_in[4];
    const float* w1     = (const float*)d_in[5];
    const float* b1     = (const float*)d_in[6];
    const float* bn1_g  = (const float*)d_in[7];
    const float* bn1_b  = (const float*)d_in[8];
    const float* w2     = (const float*)d_in[9];
    const float* b2     = (const float*)d_in[10];
    const float* gbn_g  = (const float*)d_in[11];
    const float* gbn_b  = (const float*)d_in[12];
    const float* gcn_w  = (const float*)d_in[13];
    const float* gcn_b  = (const float*)d_in[14];

    float* out = (float*)d_out;
    float* ws  = (float*)d_ws;

    // workspace layout (float units)
    float* P_part  = ws;                                   // 8,388,608
    float* qs_part = P_part + (size_t)KC * NSP * DCH;      // 65,536
    float* hA      = qs_part + (size_t)KC * NSP;           // 131,072
    float* hB      = hA + NSP * DCH;                       // 131,072
    float* dinvb   = hB + NSP * DCH;                       // 1,024
    short* htb     = (short*)(dinvb + NSP);                // 131,072 bf16
    short* w1t     = (short*)((float*)htb + 65536);        // 28,672 bf16
    short* w2t     = (short*)((float*)w1t + 14336);        // 16,384 bf16
    float* b1f     = (float*)w2t + 8192;                   // 128
    float* b2f     = b1f + 128;                            // 128
    // GCN temporaries overlay P_part (dead after reduce_h0)
    float* m1p     = P_part;                               // 4*131,072
    float* hb2b    = P_part + 4 * NSP * DCH;               // 131,072
    // xfT lives in the (currently dead) d_out buffer: 128*65536 bf16 = 16 MB
    short* xfT     = (short*)d_out;

    prep_w<<<112, 256, 0, stream>>>(w1, b1, bn0_g, bn0_b, w2, b2, bn1_g, bn1_b,
                                    w1t, w2t, b1f, b2f);
    cnn_mfma<<<HWP / 128, 128, 0, stream>>>(x, w1t, b1f, w2t, b2f, xfT);
    pool_mfma<<<dim3(NSP / 128, KC), 256, 0, stream>>>(Q, xfT, P_part, qs_part);
    reduce_h0<<<(NSP * DCH) / 256, 256, 0, stream>>>(P_part, qs_part, hA);
    dinv_k<<<NSP, 256, 0, stream>>>(adj, dinvb);

    const float* hcur = hA;
    float* hnext = hB;
    for (int i = 0; i < 3; ++i) {
        hb2_k<<<(NSP * DCH) / 256, 256, 0, stream>>>(hcur, dinvb,
                                                     gbn_g + i * DCH, gbn_b + i * DCH, hb2b);
        m1_k<<<dim3(NSP / 16, 4), 256, 0, stream>>>(adj, hb2b, m1p);
        gcnw_k<<<NSP / 16, 256, 0, stream>>>(m1p, hb2b, dinvb,
                                             gcn_w + (size_t)i * DCH * DCH,
                                             gcn_b + i * DCH, hnext);
        const float* tmp = hcur;
        hcur = hnext;
        hnext = (float*)tmp;
    }

    htprep<<<(NSP * DCH) / 256, 256, 0, stream>>>(hcur, htb);
    out_mfma<<<HWP / 128, 256, 0, stream>>>(Q, htb, out);
}